// Round 1
// baseline (3562.949 us; speedup 1.0000x reference)
//
#include <hip/hip_runtime.h>
#include <hip/hip_fp16.h>

typedef _Float16 f16;
typedef _Float16 f16x8 __attribute__((ext_vector_type(8)));
typedef _Float16 f16x4 __attribute__((ext_vector_type(4)));
typedef float f32x4v __attribute__((ext_vector_type(4)));

#define S_LEN 1024
#define NS 512
#define NV 32000

#define MFMA16(a, b, c) __builtin_amdgcn_mfma_f32_16x16x32_f16((a), (b), (c), 0, 0, 0)

// ---------------------------------------------------------------------------
// ws layout:
//   u16   : [1024][4][512] f16   at offset 0        (4 MB)   u[s][b][n]
//   st16  : [1024][4][512] f16   at offset 4 MB     (4 MB)   states[s][b][n]
//   bT16  : [512][512]     f16   at offset 8 MB     (0.5 MB) bT16[n][e] = b[e][n]
// ---------------------------------------------------------------------------

// transpose fp32 [512][512] -> f16 transposed [512][512]
__global__ __launch_bounds__(256) void transpose512_f16_kernel(
        const float* __restrict__ src, f16* __restrict__ dstT) {
    int idx = blockIdx.x * 256 + threadIdx.x;   // 0 .. 262143
    int r = idx >> 9;
    int c = idx & 511;
    dstT[c * 512 + r] = (f16)src[idx];
}

// ---------------------------------------------------------------------------
// embed + input projection: u[m][n] = sum_e emb[x[m]][e] * b[e][n], m = s*4+b
// One WG = 64 tokens, K-chunks of 32, MFMA f16.
// ---------------------------------------------------------------------------
__global__ __launch_bounds__(256) void embu_kernel(
        const int* __restrict__ x, const float* __restrict__ emb,
        const f16* __restrict__ bT, f16* __restrict__ u16) {
    __shared__ f16 embA[64 * 40];   // [64 tok][32k + pad8]
    __shared__ f16 Bt[512 * 40];    // [512 n][32k + pad8]
    __shared__ int xi[64];

    int t = threadIdx.x;
    int wg = blockIdx.x;
    if (t < 64) {
        int m = wg * 64 + t;
        int bb = m & 3, ss = m >> 2;
        xi[t] = x[bb * S_LEN + ss];
    }
    __syncthreads();

    int wv = t >> 6, l = t & 63, lr = l & 15, lg = l >> 4;

    f32x4v acc[32];
#pragma unroll
    for (int i = 0; i < 32; i++) acc[i] = (f32x4v){0.f, 0.f, 0.f, 0.f};

    for (int kc = 0; kc < 512; kc += 32) {
        __syncthreads();
        // stage embA: 64 tokens x 32 k (fp32 -> f16)
        {
            int tk = t >> 2, c0 = (t & 3) * 8;
            const float* src = emb + (size_t)xi[tk] * NS + kc + c0;
            float4 v0 = *(const float4*)src;
            float4 v1 = *(const float4*)(src + 4);
            f16x8 h;
            h[0] = (f16)v0.x; h[1] = (f16)v0.y; h[2] = (f16)v0.z; h[3] = (f16)v0.w;
            h[4] = (f16)v1.x; h[5] = (f16)v1.y; h[6] = (f16)v1.z; h[7] = (f16)v1.w;
            *(f16x8*)&embA[tk * 40 + c0] = h;
        }
        // stage Bt: 512 n-rows x 32 k from pre-transposed bT16
        {
            int c0 = (t & 3) * 8;
            int n0 = t >> 2;
#pragma unroll
            for (int r = 0; r < 8; r++) {
                int n = r * 64 + n0;
                f16x8 v = *(const f16x8*)&bT[n * 512 + kc + c0];
                *(f16x8*)&Bt[n * 40 + c0] = v;
            }
        }
        __syncthreads();

        f16x8 af = *(const f16x8*)&embA[(wv * 16 + lr) * 40 + 8 * lg];
#pragma unroll
        for (int vt = 0; vt < 32; vt++) {
            f16x8 bf = *(const f16x8*)&Bt[(vt * 16 + lr) * 40 + 8 * lg];
            acc[vt] = MFMA16(af, bf, acc[vt]);
        }
    }

    // epilogue: u16[m][n], m = wg*64 + wv*16 + 4*lg + i, n = vt*16 + lr
    int m0 = wg * 64 + wv * 16 + 4 * lg;
#pragma unroll
    for (int vt = 0; vt < 32; vt++) {
        int n = vt * 16 + lr;
#pragma unroll
        for (int i = 0; i < 4; i++) {
            u16[(size_t)(m0 + i) * NS + n] = (f16)acc[vt][i];
        }
    }
}

// ---------------------------------------------------------------------------
// scan: single workgroup (512 threads / 8 waves) on one CU.
// s_{t+1} = tanh(s_t @ a + u_t). A in f16: k-slices 0..11 in VGPR fragments,
// k-slices 12..15 in LDS (transposed). State in LDS, rows 0..3 = batches.
// ---------------------------------------------------------------------------
#define SCAN_LDS_BYTES (512 * 136 * 2 + 16 * 520 * 2)   // 139264 + 16640 = 155904

__global__ __launch_bounds__(512) void scan_kernel(
        const float* __restrict__ a, const f16* __restrict__ u16,
        f16* __restrict__ st16) {
    extern __shared__ char smem[];
    f16* At = (f16*)smem;                   // [512 n][128 k + pad8 = 136]
    f16* Sb = (f16*)(smem + 512 * 136 * 2); // [16 m][512 n + pad8 = 520]

    int t = threadIdx.x;
    int w = t >> 6, l = t & 63, lr = l & 15, lg = l >> 4;
    int nbase = w * 64;

    // zero state buffer (all 16 rows deterministic)
    for (int i = t; i < 16 * 520; i += 512) Sb[i] = (f16)0.f;

    // stage At: a rows k in [384,512) transposed -> At[n][k-384]
    for (int i = t; i < 512 * 128; i += 512) {
        int krel = i >> 9;
        int n = i & 511;
        At[n * 136 + krel] = (f16)a[(size_t)(384 + krel) * NS + n];
    }

    // load stationary register fragments: k-slices 0..11
    f16x8 afr[4][12];
#pragma unroll
    for (int tt = 0; tt < 4; tt++) {
#pragma unroll
        for (int ks = 0; ks < 12; ks++) {
            f16x8 h;
#pragma unroll
            for (int j = 0; j < 8; j++) {
                int k = ks * 32 + 8 * lg + j;
                int n = nbase + tt * 16 + lr;
                h[j] = (f16)a[(size_t)k * NS + n];
            }
            afr[tt][ks] = h;
        }
    }

    // prefetch u for step 0
    float upf[16];
#pragma unroll
    for (int i = 0; i < 16; i++) upf[i] = 0.f;
    if (l < 16) {
#pragma unroll
        for (int tt = 0; tt < 4; tt++) {
#pragma unroll
            for (int bb = 0; bb < 4; bb++) {
                upf[tt * 4 + bb] =
                    (float)u16[(size_t)bb * NS + nbase + tt * 16 + l];
            }
        }
    }

    __syncthreads();

#pragma unroll 1
    for (int s = 0; s < S_LEN; s++) {
        // init accumulators with u (rows 0..3 valid; rows 4..15 = 0, discarded)
        f32x4v acc[4];
#pragma unroll
        for (int tt = 0; tt < 4; tt++) {
            acc[tt][0] = upf[tt * 4 + 0];
            acc[tt][1] = upf[tt * 4 + 1];
            acc[tt][2] = upf[tt * 4 + 2];
            acc[tt][3] = upf[tt * 4 + 3];
        }
        // prefetch u for next step (hidden under this step's MFMAs)
        if (l < 16) {
            int sn = (s + 1 < S_LEN) ? (s + 1) : (S_LEN - 1);
#pragma unroll
            for (int tt = 0; tt < 4; tt++) {
#pragma unroll
                for (int bb = 0; bb < 4; bb++) {
                    upf[tt * 4 + bb] =
                        (float)u16[((size_t)sn * 4 + bb) * NS + nbase + tt * 16 + l];
                }
            }
        }

        // Y = S @ A : k-slices 0..11 from register fragments
#pragma unroll
        for (int ks = 0; ks < 12; ks++) {
            f16x8 sf = *(const f16x8*)&Sb[lr * 520 + ks * 32 + 8 * lg];
#pragma unroll
            for (int tt = 0; tt < 4; tt++)
                acc[tt] = MFMA16(sf, afr[tt][ks], acc[tt]);
        }
        // k-slices 12..15 from LDS
#pragma unroll
        for (int ks = 12; ks < 16; ks++) {
            f16x8 sf = *(const f16x8*)&Sb[lr * 520 + ks * 32 + 8 * lg];
#pragma unroll
            for (int tt = 0; tt < 4; tt++) {
                f16x8 bf = *(const f16x8*)&At[(nbase + tt * 16 + lr) * 136 +
                                              (ks - 12) * 32 + 8 * lg];
                acc[tt] = MFMA16(sf, bf, acc[tt]);
            }
        }

        __syncthreads();   // all waves done reading Sb

        if (l < 16) {
#pragma unroll
            for (int tt = 0; tt < 4; tt++) {
                int n = nbase + tt * 16 + l;
#pragma unroll
                for (int i = 0; i < 4; i++) {
                    float y = acc[tt][i];
                    float ez = __expf(2.f * y);
                    y = 1.f - 2.f / (ez + 1.f);   // tanh
                    f16 h = (f16)y;
                    Sb[i * 520 + n] = h;
                    st16[((size_t)s * 4 + i) * NS + n] = h;
                }
            }
        }

        __syncthreads();   // new state visible to all waves
    }
}

// ---------------------------------------------------------------------------
// readout: out[b][s][v] = states[s*4+b] . c_w[v] + c_b[v]
// BM=256, BN=128, BK=64, 512 threads / 8 waves (4x2), each wave 64x64.
// ---------------------------------------------------------------------------
__global__ __launch_bounds__(512) void readout_kernel(
        const f16* __restrict__ st16, const float* __restrict__ cw,
        const float* __restrict__ cb, float* __restrict__ out) {
    __shared__ f16 Ast[256 * 72];   // [256 m][64 k + pad8]
    __shared__ f16 Bw[128 * 72];    // [128 v][64 k + pad8]

    int t = threadIdx.x;
    int bidx = blockIdx.x;
    int bn = bidx % 250;
    int bm = bidx / 250;
    int w = t >> 6, l = t & 63, lr = l & 15, lg = l >> 4;
    int wr = w >> 1, wc = w & 1;

    f32x4v acc[4][4];
#pragma unroll
    for (int i = 0; i < 4; i++)
#pragma unroll
        for (int j = 0; j < 4; j++) acc[i][j] = (f32x4v){0.f, 0.f, 0.f, 0.f};

    for (int kc = 0; kc < 512; kc += 64) {
        __syncthreads();
        // stage A: states16, 256 rows x 64 k (f16 copy)
#pragma unroll
        for (int q = 0; q < 4; q++) {
            int idx = q * 512 + t;
            int row = idx >> 3;
            int c0 = (idx & 7) * 8;
            f16x8 v = *(const f16x8*)&st16[(size_t)(bm * 256 + row) * NS + kc + c0];
            *(f16x8*)&Ast[row * 72 + c0] = v;
        }
        // stage B: c_w fp32 -> f16, 128 rows x 64 k
#pragma unroll
        for (int q = 0; q < 4; q++) {
            int idx = q * 512 + t;
            int row = idx >> 4;
            int c0 = (idx & 15) * 4;
            float4 v = *(const float4*)&cw[(size_t)(bn * 128 + row) * NS + kc + c0];
            f16x4 h;
            h[0] = (f16)v.x; h[1] = (f16)v.y; h[2] = (f16)v.z; h[3] = (f16)v.w;
            *(f16x4*)&Bw[row * 72 + c0] = h;
        }
        __syncthreads();

#pragma unroll
        for (int ks = 0; ks < 2; ks++) {
            f16x8 af[4], bf[4];
#pragma unroll
            for (int mt = 0; mt < 4; mt++)
                af[mt] = *(const f16x8*)&Ast[(wr * 64 + mt * 16 + lr) * 72 +
                                             ks * 32 + 8 * lg];
#pragma unroll
            for (int vt = 0; vt < 4; vt++)
                bf[vt] = *(const f16x8*)&Bw[(wc * 64 + vt * 16 + lr) * 72 +
                                            ks * 32 + 8 * lg];
#pragma unroll
            for (int mt = 0; mt < 4; mt++)
#pragma unroll
                for (int vt = 0; vt < 4; vt++)
                    acc[mt][vt] = MFMA16(af[mt], bf[vt], acc[mt][vt]);
        }
    }

    // epilogue: bias + scatter rows to out[b][s][v]
    float bias[4];
#pragma unroll
    for (int vt = 0; vt < 4; vt++)
        bias[vt] = cb[bn * 128 + wc * 64 + vt * 16 + lr];

#pragma unroll
    for (int mt = 0; mt < 4; mt++) {
#pragma unroll
        for (int i = 0; i < 4; i++) {
            int m = bm * 256 + wr * 64 + mt * 16 + 4 * lg + i;
            int bb = m & 3, ss = m >> 2;
            float* orow = out + (size_t)(bb * S_LEN + ss) * NV + bn * 128 + wc * 64;
#pragma unroll
            for (int vt = 0; vt < 4; vt++)
                orow[vt * 16 + lr] = acc[mt][vt][i] + bias[vt];
        }
    }
}

// ---------------------------------------------------------------------------
extern "C" void kernel_launch(void* const* d_in, const int* in_sizes, int n_in,
                              void* d_out, int out_size, void* d_ws, size_t ws_size,
                              hipStream_t stream) {
    (void)in_sizes; (void)n_in; (void)out_size; (void)ws_size;

    const int*   x   = (const int*)d_in[0];
    const float* emb = (const float*)d_in[1];
    const float* a   = (const float*)d_in[2];
    const float* bm  = (const float*)d_in[3];
    const float* cw  = (const float*)d_in[4];
    const float* cb  = (const float*)d_in[5];
    float* out = (float*)d_out;

    char* ws = (char*)d_ws;
    f16* u16  = (f16*)(ws);
    f16* st16 = (f16*)(ws + (4u << 20));
    f16* bT16 = (f16*)(ws + (8u << 20));

    hipFuncSetAttribute(reinterpret_cast<const void*>(scan_kernel),
                        hipFuncAttributeMaxDynamicSharedMemorySize,
                        SCAN_LDS_BYTES);

    transpose512_f16_kernel<<<1024, 256, 0, stream>>>(bm, bT16);
    embu_kernel<<<64, 256, 0, stream>>>(x, emb, bT16, u16);
    scan_kernel<<<1, 512, SCAN_LDS_BYTES, stream>>>(a, u16, st16);
    readout_kernel<<<16 * 250, 512, 0, stream>>>(st16, cw, cb, out);
}